// Round 3
// 319.296 us; speedup vs baseline: 1.0168x; 1.0168x over previous
//
#include <hip/hip_runtime.h>
#include <hip/hip_bf16.h>

// DOMINANT GCN autoencoder on MI355X.
// R13 (resubmit — previous round was an infra failure, no kernel signal).
// R11 structure (verified passing) + register-preloaded edge indices.
// R12's failure root-caused to DIVERGENT trip counts around __shfl: per-half
// pair counts differ for odd degrees, so shuffles read from inactive lanes
// (ds_bpermute from exec=0 is undefined). R13 makes the gather loop
// wave-uniform: main loop bounded by c>>1 (valid for both halves), predicated
// tail with cndmask (no branches), all lanes active at every __shfl.
// Keeps: 1 coalesced csr_src[beg+lane] preload per node (kills the dependent
// index-load -> gather chain), 32-bit gather addressing.

// ---------------- CSR build ----------------

__global__ __launch_bounds__(256) void init_k(int* __restrict__ deg, int Npad) {
    int i = blockIdx.x * 256 + threadIdx.x;
    if (i < Npad) deg[i] = 0;
}

__global__ __launch_bounds__(256) void hist_deg(const int* __restrict__ dst,
                                                int* __restrict__ deg, int E) {
    int e = blockIdx.x * 256 + threadIdx.x;
    if (e < E) atomicAdd(&deg[dst[e]], 1);
}

__global__ __launch_bounds__(256) void scan_phase1(const int* __restrict__ deg,
                                                   int* __restrict__ block_sums) {
    int b = blockIdx.x, t = threadIdx.x;
    const int4* p = reinterpret_cast<const int4*>(deg + (size_t)b * 2048);
    int4 a = p[t * 2], c = p[t * 2 + 1];
    int s = a.x + a.y + a.z + a.w + c.x + c.y + c.z + c.w;
#pragma unroll
    for (int off = 32; off; off >>= 1) s += __shfl_down(s, off);
    __shared__ int wsum[4];
    if ((t & 63) == 0) wsum[t >> 6] = s;
    __syncthreads();
    if (t == 0) block_sums[b] = wsum[0] + wsum[1] + wsum[2] + wsum[3];
}

__global__ __launch_bounds__(256) void scan_phase2(const int* __restrict__ block_sums,
                                                   int* __restrict__ block_off,
                                                   int* __restrict__ row_ptr,
                                                   int B, int N) {
    __shared__ int s[256];
    int t = threadIdx.x;
    int v = (t < B) ? block_sums[t] : 0;
    s[t] = v;
    __syncthreads();
#pragma unroll
    for (int off = 1; off < 256; off <<= 1) {
        int u = (t >= off) ? s[t - off] : 0;
        __syncthreads();
        s[t] += u;
        __syncthreads();
    }
    if (t < B) block_off[t] = s[t] - v;
    if (t == 255) row_ptr[N] = s[255];
}

__global__ __launch_bounds__(256) void scan_phase3(const int* __restrict__ deg,
                                                   const int* __restrict__ block_off,
                                                   int* __restrict__ row_ptr,
                                                   float* __restrict__ dis, int N) {
    int b = blockIdx.x, t = threadIdx.x;
    int base = b * 2048 + t * 8;
    const int4* p = reinterpret_cast<const int4*>(deg + base);
    int4 a = p[0], c = p[1];
    int d[8] = {a.x, a.y, a.z, a.w, c.x, c.y, c.z, c.w};
    int pre[8], s = 0;
#pragma unroll
    for (int j = 0; j < 8; ++j) { pre[j] = s; s += d[j]; }
    __shared__ int ls[256];
    ls[t] = s;
    __syncthreads();
#pragma unroll
    for (int off = 1; off < 256; off <<= 1) {
        int u = (t >= off) ? ls[t - off] : 0;
        __syncthreads();
        ls[t] += u;
        __syncthreads();
    }
    int excl = ls[t] - s + block_off[b];
#pragma unroll
    for (int j = 0; j < 8; ++j) {
        int i = base + j;
        if (i < N) {
            row_ptr[i] = excl + pre[j];
            dis[i] = rsqrtf((float)(d[j] + 1));
        }
    }
}

__global__ __launch_bounds__(256) void fill_csr(const int* __restrict__ src,
                                                const int* __restrict__ dst,
                                                const int* __restrict__ row_ptr,
                                                int* __restrict__ deg,
                                                int* __restrict__ csr_src, int E) {
    int e = blockIdx.x * 256 + threadIdx.x;
    if (e < E) {
        int d = dst[e];
        int old = atomicSub(&deg[d], 1);
        csr_src[row_ptr[d] + old - 1] = src[e];
    }
}

// ---------------- helpers ----------------

__device__ __forceinline__ ushort r16(float f) {
    __hip_bfloat16 h = __float2bfloat16(f);   // round-to-nearest-even
    return *reinterpret_cast<ushort*>(&h);
}
__device__ __forceinline__ float bf_lo(unsigned u) {
    return __builtin_bit_cast(float, u << 16);
}
__device__ __forceinline__ float bf_hi(unsigned u) {
    return __builtin_bit_cast(float, u & 0xFFFF0000u);
}

// Half-wave gather-sum from a [N][32]-uint bf16 table, register-indexed.
// One coalesced load puts csr_src[beg+lane] (first 64 edges) in a VGPR; the
// gather loop broadcasts indices via __shfl, so gather loads have no
// dependent index-load latency. Control flow is WAVE-UNIFORM: main loop
// bounded by pfull=c>>1 (all 4 edges valid for BOTH halves), tail runs the
// same trip count on all lanes with cndmask predication (sl clamp + u zero).
// Every __shfl executes with all 64 lanes active. Returns full neighbor sums
// on ALL lanes (post shfl_xor).
__device__ __forceinline__ void gather_sum_reg(const unsigned* __restrict__ G,
                                               const int* __restrict__ csr_src,
                                               int beg, int len,
                                               int lane, int h, int fl,
                                               float& lo_out, float& hi_out) {
    int idx = 0;
    if (len > 0) idx = csr_src[beg + (lane < len ? lane : len - 1)];

    int c     = len < 64 ? len : 64;
    int pM    = (c + 1) >> 1;   // h=0 edge count (the larger)
    int pfull = c >> 1;         // count for which BOTH halves' edges are valid

    float a0 = 0.f, a1 = 0.f, a2 = 0.f, a3 = 0.f;
    float b0 = 0.f, b1 = 0.f, b2 = 0.f, b3 = 0.f;

    int k = 0;
    for (; k + 4 <= pfull; k += 4) {
        int e  = h + 2 * k;
        int s0 = __shfl(idx, e);
        int s1 = __shfl(idx, e + 2);
        int s2 = __shfl(idx, e + 4);
        int s3 = __shfl(idx, e + 6);
        unsigned u0 = G[(unsigned)s0 * 32u + fl];
        unsigned u1 = G[(unsigned)s1 * 32u + fl];
        unsigned u2 = G[(unsigned)s2 * 32u + fl];
        unsigned u3 = G[(unsigned)s3 * 32u + fl];
        a0 += bf_lo(u0); b0 += bf_hi(u0);
        a1 += bf_lo(u1); b1 += bf_hi(u1);
        a2 += bf_lo(u2); b2 += bf_hi(u2);
        a3 += bf_lo(u3); b3 += bf_hi(u3);
    }
    for (; k < pM; ++k) {                  // wave-uniform trips; predicated
        int e  = h + 2 * k;
        int sl = e < c ? e : 0;            // keep shfl source in-range
        int s  = __shfl(idx, sl);
        unsigned u = G[(unsigned)s * 32u + fl];
        u = (e < c) ? u : 0u;              // cndmask, no branch
        a0 += bf_lo(u); b0 += bf_hi(u);
    }
    // degree > 64 spill (parity-h edges from 64+h) — memory-indexed path
    for (int e2 = 64 + h; e2 < len; e2 += 2) {
        unsigned u = G[(unsigned)csr_src[beg + e2] * 32u + fl];
        a0 += bf_lo(u); b0 += bf_hi(u);
    }

    float lo = (a0 + a1) + (a2 + a3);
    float hi = (b0 + b1) + (b2 + b3);
    lo += __shfl_xor(lo, 32);
    hi += __shfl_xor(hi, 32);
    lo_out = lo;  hi_out = hi;
}

// ---------------- GEMM, row-scale + bf16 epilogue (layer 1) ----------------
template <int K, int DOUT>
__global__ __launch_bounds__(256) void gemm_scale(const float* __restrict__ A,
                                                  const float* __restrict__ W,
                                                  const float* __restrict__ dis,
                                                  ushort* __restrict__ G16, int N) {
    constexpr int CG   = DOUT / 4;
    constexpr int RG   = 256 / CG;
    constexpr int ROWS = RG * 4;
    constexpr int LDA  = K + 4;

    __shared__ __align__(16) float a_lds[ROWS * LDA];
    __shared__ __align__(16) float w_lds[K * DOUT];

    int t    = threadIdx.x;
    int row0 = blockIdx.x * ROWS;

    constexpr int WF4 = K * DOUT / 4;
    for (int q = t; q < WF4; q += 256)
        reinterpret_cast<float4*>(w_lds)[q] =
            reinterpret_cast<const float4*>(W)[q];

    constexpr int AF4 = ROWS * K / 4;
    for (int q = t; q < AF4; q += 256) {
        int r  = q / (K / 4);
        int kc = q % (K / 4);
        float4 v = make_float4(0.f, 0.f, 0.f, 0.f);
        int gr = row0 + r;
        if (gr < N)
            v = reinterpret_cast<const float4*>(A + (size_t)gr * K)[kc];
        *reinterpret_cast<float4*>(&a_lds[r * LDA + kc * 4]) = v;
    }
    __syncthreads();

    int c0 = (t % CG) * 4;
    int r0 = (t / CG) * 4;

    float4 acc[4] = {};
#pragma unroll 1
    for (int k = 0; k < K; k += 4) {
        float4 w0 = *reinterpret_cast<const float4*>(&w_lds[(k + 0) * DOUT + c0]);
        float4 w1 = *reinterpret_cast<const float4*>(&w_lds[(k + 1) * DOUT + c0]);
        float4 w2 = *reinterpret_cast<const float4*>(&w_lds[(k + 2) * DOUT + c0]);
        float4 w3 = *reinterpret_cast<const float4*>(&w_lds[(k + 3) * DOUT + c0]);
#pragma unroll
        for (int j = 0; j < 4; ++j) {
            float4 a4 = *reinterpret_cast<const float4*>(&a_lds[(r0 + j) * LDA + k]);
            acc[j].x += a4.x * w0.x + a4.y * w1.x + a4.z * w2.x + a4.w * w3.x;
            acc[j].y += a4.x * w0.y + a4.y * w1.y + a4.z * w2.y + a4.w * w3.y;
            acc[j].z += a4.x * w0.z + a4.y * w1.z + a4.z * w2.z + a4.w * w3.z;
            acc[j].w += a4.x * w0.w + a4.y * w1.w + a4.z * w2.w + a4.w * w3.w;
        }
    }

#pragma unroll
    for (int j = 0; j < 4; ++j) {
        int gr = row0 + r0 + j;
        if (gr < N) {
            float s = dis[gr];
            float4 o = acc[j];
            ushort4 pk;
            pk.x = r16(o.x * s); pk.y = r16(o.y * s);
            pk.z = r16(o.z * s); pk.w = r16(o.w * s);
            *reinterpret_cast<ushort4*>(&G16[(size_t)gr * DOUT + c0]) = pk;
        }
    }
}

// ---------------- GEMM, bias epilogue, fp32 out (final layer) ----------------
template <int K, int DOUT>
__global__ __launch_bounds__(256) void gemm_bias(const float* __restrict__ A,
                                                 const float* __restrict__ W,
                                                 const float* __restrict__ bias,
                                                 float* __restrict__ Out, int N) {
    constexpr int CG   = DOUT / 4;
    constexpr int RG   = 256 / CG;
    constexpr int ROWS = RG * 4;
    constexpr int LDA  = K + 4;

    __shared__ __align__(16) float a_lds[ROWS * LDA];
    __shared__ __align__(16) float w_lds[K * DOUT];

    int t    = threadIdx.x;
    int row0 = blockIdx.x * ROWS;

    constexpr int WF4 = K * DOUT / 4;
    for (int q = t; q < WF4; q += 256)
        reinterpret_cast<float4*>(w_lds)[q] =
            reinterpret_cast<const float4*>(W)[q];

    constexpr int AF4 = ROWS * K / 4;
    for (int q = t; q < AF4; q += 256) {
        int r  = q / (K / 4);
        int kc = q % (K / 4);
        float4 v = make_float4(0.f, 0.f, 0.f, 0.f);
        int gr = row0 + r;
        if (gr < N)
            v = reinterpret_cast<const float4*>(A + (size_t)gr * K)[kc];
        *reinterpret_cast<float4*>(&a_lds[r * LDA + kc * 4]) = v;
    }
    __syncthreads();

    int c0 = (t % CG) * 4;
    int r0 = (t / CG) * 4;

    float4 acc[4] = {};
#pragma unroll 1
    for (int k = 0; k < K; k += 4) {
        float4 w0 = *reinterpret_cast<const float4*>(&w_lds[(k + 0) * DOUT + c0]);
        float4 w1 = *reinterpret_cast<const float4*>(&w_lds[(k + 1) * DOUT + c0]);
        float4 w2 = *reinterpret_cast<const float4*>(&w_lds[(k + 2) * DOUT + c0]);
        float4 w3 = *reinterpret_cast<const float4*>(&w_lds[(k + 3) * DOUT + c0]);
#pragma unroll
        for (int j = 0; j < 4; ++j) {
            float4 a4 = *reinterpret_cast<const float4*>(&a_lds[(r0 + j) * LDA + k]);
            acc[j].x += a4.x * w0.x + a4.y * w1.x + a4.z * w2.x + a4.w * w3.x;
            acc[j].y += a4.x * w0.y + a4.y * w1.y + a4.z * w2.y + a4.w * w3.y;
            acc[j].z += a4.x * w0.z + a4.y * w1.z + a4.z * w2.z + a4.w * w3.z;
            acc[j].w += a4.x * w0.w + a4.y * w1.w + a4.z * w2.w + a4.w * w3.w;
        }
    }

    float4 b4v = *reinterpret_cast<const float4*>(&bias[c0]);
#pragma unroll
    for (int j = 0; j < 4; ++j) {
        int gr = row0 + r0 + j;
        if (gr < N) {
            float4 o = acc[j];
            o.x += b4v.x; o.y += b4v.y; o.z += b4v.z; o.w += b4v.w;
            reinterpret_cast<float4*>(Out + (size_t)gr * DOUT)[c0 / 4] = o;
        }
    }
}

// ---------------- Fused aggregate + next-layer 64->64 GEMM ------------------
// R11-verified structure: 2 nodes per wave SERIAL (j loop), h==0 epilogue.
// v = relu(dis[n]*(G[n]+sum)+bias); Gout[n] = bf16(dis[n]*(v@Wn)).
// WRITE_F32: also emit v as fp32 (the z output).
template <bool WRITE_F32>
__global__ __launch_bounds__(256) void agg_gemm_table(
    const unsigned* __restrict__ G,
    const int* __restrict__ row_ptr,
    const int* __restrict__ csr_src,
    const float* __restrict__ dis,
    const float* __restrict__ bias,
    const float* __restrict__ Wn,        // [64][64] fp32
    unsigned* __restrict__ Gout,
    float* __restrict__ Zout,
    int N) {
    __shared__ __align__(16) float w_lds[64 * 64];
    __shared__ __align__(16) float a_buf[4][64];

    int t = threadIdx.x;
    for (int q = t; q < 64 * 64 / 4; q += 256)
        reinterpret_cast<float4*>(w_lds)[q] =
            reinterpret_cast<const float4*>(Wn)[q];
    __syncthreads();

    int wave = t >> 6, lane = t & 63;
    int h = lane >> 5, fl = lane & 31;

    for (int j = 0; j < 2; ++j) {
        int n = (blockIdx.x * 4 + wave) * 2 + j;
        if (n >= N) break;   // wave-uniform

        int beg = row_ptr[n];
        int len = row_ptr[n + 1] - beg;
        float lo, hi;
        gather_sum_reg(G, csr_src, beg, len, lane, h, fl, lo, hi);

        float dn = dis[n];
        unsigned us = G[(unsigned)n * 32u + fl];    // self-loop pair
        float2 b2 = reinterpret_cast<const float2*>(bias)[fl];
        float vlo = fmaxf(dn * (lo + bf_lo(us)) + b2.x, 0.f);
        float vhi = fmaxf(dn * (hi + bf_hi(us)) + b2.y, 0.f);

        if (h == 0) {
            *reinterpret_cast<float2*>(&a_buf[wave][2 * fl]) =
                make_float2(vlo, vhi);
            if (WRITE_F32)
                reinterpret_cast<float2*>(Zout)[(size_t)n * 32 + fl] =
                    make_float2(vlo, vhi);
        }
        __builtin_amdgcn_wave_barrier();   // a_buf write -> read (in-order DS)

        // matvec: this lane owns output column `lane`
        float y0 = 0.f, y1 = 0.f, y2 = 0.f, y3 = 0.f;
        for (int k = 0; k < 64; k += 4) {
            float4 a4 = *reinterpret_cast<const float4*>(&a_buf[wave][k]);
            y0 += a4.x * w_lds[(k + 0) * 64 + lane];
            y1 += a4.y * w_lds[(k + 1) * 64 + lane];
            y2 += a4.z * w_lds[(k + 2) * 64 + lane];
            y3 += a4.w * w_lds[(k + 3) * 64 + lane];
        }
        float y = (y0 + y1) + (y2 + y3);
        __builtin_amdgcn_wave_barrier();   // reads done before next j's write

        float ylo = __shfl(y, 2 * fl);
        float yhi = __shfl(y, 2 * fl + 1);
        if (h == 0) {
            unsigned pk = (unsigned)r16(dn * ylo) | ((unsigned)r16(dn * yhi) << 16);
            Gout[(unsigned)n * 32u + fl] = pk;
        }
    }
}

// ---------------- Plain aggregations ----------------------------------------
// Layer 3: s3 = bf16(dis * relu(agg + b3)) table. 1 node/wave (R11 config).
__global__ __launch_bounds__(256) void aggregate_s3(const unsigned* __restrict__ G,
                                                    const int* __restrict__ row_ptr,
                                                    const int* __restrict__ csr_src,
                                                    const float* __restrict__ dis,
                                                    const float* __restrict__ bias,
                                                    unsigned* __restrict__ Out, int N) {
    int wave = threadIdx.x >> 6;
    int lane = threadIdx.x & 63;
    int n = blockIdx.x * 4 + wave;
    if (n >= N) return;
    int h = lane >> 5, fl = lane & 31;

    int beg = row_ptr[n];
    int len = row_ptr[n + 1] - beg;
    float lo, hi;
    gather_sum_reg(G, csr_src, beg, len, lane, h, fl, lo, hi);

    if (h == 0) {
        unsigned us = G[(unsigned)n * 32u + fl];
        float dn = dis[n];
        float2 b2 = reinterpret_cast<const float2*>(bias)[fl];
        float vlo = fmaxf(dn * (lo + bf_lo(us)) + b2.x, 0.f);
        float vhi = fmaxf(dn * (hi + bf_hi(us)) + b2.y, 0.f);
        // s3 = bf16(dis[n] * v) — extra dn for the reassociated layer 4
        unsigned pk = (unsigned)r16(dn * vlo) | ((unsigned)r16(dn * vhi) << 16);
        Out[(unsigned)n * 32u + fl] = pk;
    }
}

// Layer 4 aggregate: t = dis[n]*(s3[n]+sum s3[src]) (fp32, no bias/relu).
__global__ __launch_bounds__(256) void aggregate_t(const unsigned* __restrict__ G,
                                                   const int* __restrict__ row_ptr,
                                                   const int* __restrict__ csr_src,
                                                   const float* __restrict__ dis,
                                                   float* __restrict__ Out, int N) {
    int wave = threadIdx.x >> 6;
    int lane = threadIdx.x & 63;
    int n = blockIdx.x * 4 + wave;
    if (n >= N) return;
    int h = lane >> 5, fl = lane & 31;

    int beg = row_ptr[n];
    int len = row_ptr[n + 1] - beg;
    float lo, hi;
    gather_sum_reg(G, csr_src, beg, len, lane, h, fl, lo, hi);

    if (h == 0) {
        unsigned us = G[(unsigned)n * 32u + fl];
        float dn = dis[n];
        reinterpret_cast<float2*>(Out)[(size_t)n * 32 + fl] =
            make_float2(dn * (lo + bf_lo(us)), dn * (hi + bf_hi(us)));
    }
}

// ---------------- Launch ----------------

extern "C" void kernel_launch(void* const* d_in, const int* in_sizes, int n_in,
                              void* d_out, int out_size, void* d_ws, size_t ws_size,
                              hipStream_t stream) {
    const float* x     = (const float*)d_in[0];
    const int*   edges = (const int*)d_in[1];   // [2, E] row-major
    const float* W1 = (const float*)d_in[2];
    const float* b1 = (const float*)d_in[3];
    const float* W2 = (const float*)d_in[4];
    const float* b2 = (const float*)d_in[5];
    const float* W3 = (const float*)d_in[6];
    const float* b3 = (const float*)d_in[7];
    const float* W4 = (const float*)d_in[8];
    const float* b4 = (const float*)d_in[9];

    const int DIN = 128, DH = 64;
    int N = in_sizes[0] / DIN;
    int E = in_sizes[1] / 2;

    const int* e_src = edges;
    const int* e_dst = edges + E;

    float* out   = (float*)d_out;
    float* x_hat = out;                       // [N,128]
    float* z     = out + (size_t)N * DIN;     // [N,64]

    int B    = (N + 2047) / 2048;
    int Npad = B * 2048;

    char*  ws  = (char*)d_ws;
    size_t woff = 0;
    auto carve = [&](size_t bytes) {
        void* p = ws + woff;
        woff = (woff + bytes + 255) & ~(size_t)255;
        return p;
    };
    float*    dis        = (float*)   carve((size_t)N * 4);
    int*      deg        = (int*)     carve((size_t)Npad * 4);
    int*      row_ptr    = (int*)     carve((size_t)(N + 1) * 4);
    int*      csr_src    = (int*)     carve((size_t)E * 4);
    int*      block_sums = (int*)     carve((size_t)B * 4);
    int*      block_off  = (int*)     carve((size_t)B * 4);
    unsigned* gA         = (unsigned*)carve((size_t)N * DH * 2);  // ping
    unsigned* gB         = (unsigned*)carve((size_t)N * DH * 2);  // pong
    float*    t          = (float*)   carve((size_t)N * DH * 4);  // layer-4 agg
    (void)ws_size;

    int nb_e   = (E + 255) / 256;
    int nb_agg = (N + 3) / 4;
    int nb_f   = (N + 7) / 8;      // fused: 4 waves x 2 nodes per block

    // CSR build
    init_k<<<(Npad + 255) / 256, 256, 0, stream>>>(deg, Npad);
    hist_deg<<<nb_e, 256, 0, stream>>>(e_dst, deg, E);
    scan_phase1<<<B, 256, 0, stream>>>(deg, block_sums);
    scan_phase2<<<1, 256, 0, stream>>>(block_sums, block_off, row_ptr, B, N);
    scan_phase3<<<B, 256, 0, stream>>>(deg, block_off, row_ptr, dis, N);
    fill_csr<<<nb_e, 256, 0, stream>>>(e_src, e_dst, row_ptr, deg, csr_src, E);

    // Layer 1 GEMM: g1 = bf16(dis*(x @ W1)) -> gA
    gemm_scale<128, 64><<<(N + 63) / 64, 256, 0, stream>>>(
        x, W1, dis, (ushort*)gA, N);

    // Fused 1->2: h = relu(agg(gA)+b1); gB = bf16(dis*(h@W2))
    agg_gemm_table<false><<<nb_f, 256, 0, stream>>>(
        gA, row_ptr, csr_src, dis, b1, W2, gB, nullptr, N);

    // Fused 2->3: z = relu(agg(gB)+b2) -> d_out; gA = bf16(dis*(z@W3))
    agg_gemm_table<true><<<nb_f, 256, 0, stream>>>(
        gB, row_ptr, csr_src, dis, b2, W3, gA, z, N);

    // Layer 3: s3 = bf16(dis * relu(agg(gA)+b3)) -> gB
    aggregate_s3<<<nb_agg, 256, 0, stream>>>(
        gA, row_ptr, csr_src, dis, b3, gB, N);

    // Layer 4 (unfused): t = dis*agg(gB); x_hat = t @ W4 + b4
    aggregate_t<<<nb_agg, 256, 0, stream>>>(
        gB, row_ptr, csr_src, dis, t, N);
    gemm_bias<64, 128><<<(N + 31) / 32, 256, 0, stream>>>(t, W4, b4, x_hat, N);
}

// Round 4
// 298.726 us; speedup vs baseline: 1.0868x; 1.0689x over previous
//
#include <hip/hip_runtime.h>
#include <hip/hip_bf16.h>

// DOMINANT GCN autoencoder on MI355X.
// R14: maximize gather MLP with wave-uniform discipline (R13-verified).
//  - 8-wide fully-predicated gather batches: loop bound pM=(max(c)+1)>>1 is
//    wave-uniform; slots zeroed via cndmask (e<c). One batch covers deg<=16
//    -> single load-latency exposure per node, no serial tail.
//  - 2 nodes/wave in ALL aggregation passes, A+B gathers issued jointly
//    (16 loads in flight); fused kernels use dual matvec sharing W LDS reads;
//    plain kernels write per-half (h==0 -> node A, h==1 -> node B, hasB guard).
//  - every __shfl executes with all 64 lanes active (no divergent shuffles).
// CSR build, layer-1 GEMM, layer-4 GEMM unchanged from R13.

// ---------------- CSR build ----------------

__global__ __launch_bounds__(256) void init_k(int* __restrict__ deg, int Npad) {
    int i = blockIdx.x * 256 + threadIdx.x;
    if (i < Npad) deg[i] = 0;
}

__global__ __launch_bounds__(256) void hist_deg(const int* __restrict__ dst,
                                                int* __restrict__ deg, int E) {
    int e = blockIdx.x * 256 + threadIdx.x;
    if (e < E) atomicAdd(&deg[dst[e]], 1);
}

__global__ __launch_bounds__(256) void scan_phase1(const int* __restrict__ deg,
                                                   int* __restrict__ block_sums) {
    int b = blockIdx.x, t = threadIdx.x;
    const int4* p = reinterpret_cast<const int4*>(deg + (size_t)b * 2048);
    int4 a = p[t * 2], c = p[t * 2 + 1];
    int s = a.x + a.y + a.z + a.w + c.x + c.y + c.z + c.w;
#pragma unroll
    for (int off = 32; off; off >>= 1) s += __shfl_down(s, off);
    __shared__ int wsum[4];
    if ((t & 63) == 0) wsum[t >> 6] = s;
    __syncthreads();
    if (t == 0) block_sums[b] = wsum[0] + wsum[1] + wsum[2] + wsum[3];
}

__global__ __launch_bounds__(256) void scan_phase2(const int* __restrict__ block_sums,
                                                   int* __restrict__ block_off,
                                                   int* __restrict__ row_ptr,
                                                   int B, int N) {
    __shared__ int s[256];
    int t = threadIdx.x;
    int v = (t < B) ? block_sums[t] : 0;
    s[t] = v;
    __syncthreads();
#pragma unroll
    for (int off = 1; off < 256; off <<= 1) {
        int u = (t >= off) ? s[t - off] : 0;
        __syncthreads();
        s[t] += u;
        __syncthreads();
    }
    if (t < B) block_off[t] = s[t] - v;
    if (t == 255) row_ptr[N] = s[255];
}

__global__ __launch_bounds__(256) void scan_phase3(const int* __restrict__ deg,
                                                   const int* __restrict__ block_off,
                                                   int* __restrict__ row_ptr,
                                                   float* __restrict__ dis, int N) {
    int b = blockIdx.x, t = threadIdx.x;
    int base = b * 2048 + t * 8;
    const int4* p = reinterpret_cast<const int4*>(deg + base);
    int4 a = p[0], c = p[1];
    int d[8] = {a.x, a.y, a.z, a.w, c.x, c.y, c.z, c.w};
    int pre[8], s = 0;
#pragma unroll
    for (int j = 0; j < 8; ++j) { pre[j] = s; s += d[j]; }
    __shared__ int ls[256];
    ls[t] = s;
    __syncthreads();
#pragma unroll
    for (int off = 1; off < 256; off <<= 1) {
        int u = (t >= off) ? ls[t - off] : 0;
        __syncthreads();
        ls[t] += u;
        __syncthreads();
    }
    int excl = ls[t] - s + block_off[b];
#pragma unroll
    for (int j = 0; j < 8; ++j) {
        int i = base + j;
        if (i < N) {
            row_ptr[i] = excl + pre[j];
            dis[i] = rsqrtf((float)(d[j] + 1));
        }
    }
}

__global__ __launch_bounds__(256) void fill_csr(const int* __restrict__ src,
                                                const int* __restrict__ dst,
                                                const int* __restrict__ row_ptr,
                                                int* __restrict__ deg,
                                                int* __restrict__ csr_src, int E) {
    int e = blockIdx.x * 256 + threadIdx.x;
    if (e < E) {
        int d = dst[e];
        int old = atomicSub(&deg[d], 1);
        csr_src[row_ptr[d] + old - 1] = src[e];
    }
}

// ---------------- helpers ----------------

__device__ __forceinline__ ushort r16(float f) {
    __hip_bfloat16 h = __float2bfloat16(f);   // round-to-nearest-even
    return *reinterpret_cast<ushort*>(&h);
}
__device__ __forceinline__ float bf_lo(unsigned u) {
    return __builtin_bit_cast(float, u << 16);
}
__device__ __forceinline__ float bf_hi(unsigned u) {
    return __builtin_bit_cast(float, u & 0xFFFF0000u);
}

// Dual-node gather-sum from a [N][32]-uint bf16 table.
// Indices preloaded: lane i holds csr_src[beg+i] (first 64 edges, clamped).
// Gather loop: 8 slots per node per batch, loop bound pM wave-uniform
// (max over both nodes), slot validity via cndmask zeroing only (addresses
// always valid). 16 loads issue per batch -> high MLP, no serial tail.
// All __shfl with full wave active. Returns both nodes' full sums on ALL
// lanes (post shfl_xor).
__device__ __forceinline__ void gather_pair_u(const unsigned* __restrict__ G,
                                              const int* __restrict__ csr_src,
                                              int begA, int lenA,
                                              int begB, int lenB,
                                              int lane, int h, int fl,
                                              float& loA_o, float& hiA_o,
                                              float& loB_o, float& hiB_o) {
    int idxA = 0, idxB = 0;
    if (lenA > 0) idxA = csr_src[begA + (lane < lenA ? lane : lenA - 1)];
    if (lenB > 0) idxB = csr_src[begB + (lane < lenB ? lane : lenB - 1)];

    int cA = lenA < 64 ? lenA : 64;
    int cB = lenB < 64 ? lenB : 64;
    int pA = (cA + 1) >> 1;
    int pB = (cB + 1) >> 1;
    int pM = pA > pB ? pA : pB;          // wave-uniform joint bound

    float lA[4] = {0.f, 0.f, 0.f, 0.f}, hA[4] = {0.f, 0.f, 0.f, 0.f};
    float lB[4] = {0.f, 0.f, 0.f, 0.f}, hB[4] = {0.f, 0.f, 0.f, 0.f};

    for (int k = 0; k < pM; k += 8) {
        unsigned uA[8], uB[8];
        int ee[8];
#pragma unroll
        for (int i = 0; i < 8; ++i) {
            int e = h + 2 * (k + i);
            ee[i] = e;
            int sA = __shfl(idxA, e);    // e<=63 always; data validity via pred
            int sB = __shfl(idxB, e);
            uA[i] = G[(unsigned)sA * 32u + fl];
            uB[i] = G[(unsigned)sB * 32u + fl];
        }
#pragma unroll
        for (int i = 0; i < 8; ++i) {
            unsigned a = (ee[i] < cA) ? uA[i] : 0u;   // cndmask, no branch
            unsigned b = (ee[i] < cB) ? uB[i] : 0u;
            lA[i & 3] += bf_lo(a);  hA[i & 3] += bf_hi(a);
            lB[i & 3] += bf_lo(b);  hB[i & 3] += bf_hi(b);
        }
    }
    // degree > 64 spill (parity-h edges from 64+h) — memory-indexed, no shfl
    for (int e2 = 64 + h; e2 < lenA; e2 += 2) {
        unsigned u = G[(unsigned)csr_src[begA + e2] * 32u + fl];
        lA[0] += bf_lo(u); hA[0] += bf_hi(u);
    }
    for (int e2 = 64 + h; e2 < lenB; e2 += 2) {
        unsigned u = G[(unsigned)csr_src[begB + e2] * 32u + fl];
        lB[0] += bf_lo(u); hB[0] += bf_hi(u);
    }

    float lo = (lA[0] + lA[1]) + (lA[2] + lA[3]);
    float hi = (hA[0] + hA[1]) + (hA[2] + hA[3]);
    lo += __shfl_xor(lo, 32);
    hi += __shfl_xor(hi, 32);
    loA_o = lo;  hiA_o = hi;
    float lob = (lB[0] + lB[1]) + (lB[2] + lB[3]);
    float hib = (hB[0] + hB[1]) + (hB[2] + hB[3]);
    lob += __shfl_xor(lob, 32);
    hib += __shfl_xor(hib, 32);
    loB_o = lob;  hiB_o = hib;
}

// ---------------- GEMM, row-scale + bf16 epilogue (layer 1) ----------------
template <int K, int DOUT>
__global__ __launch_bounds__(256) void gemm_scale(const float* __restrict__ A,
                                                  const float* __restrict__ W,
                                                  const float* __restrict__ dis,
                                                  ushort* __restrict__ G16, int N) {
    constexpr int CG   = DOUT / 4;
    constexpr int RG   = 256 / CG;
    constexpr int ROWS = RG * 4;
    constexpr int LDA  = K + 4;

    __shared__ __align__(16) float a_lds[ROWS * LDA];
    __shared__ __align__(16) float w_lds[K * DOUT];

    int t    = threadIdx.x;
    int row0 = blockIdx.x * ROWS;

    constexpr int WF4 = K * DOUT / 4;
    for (int q = t; q < WF4; q += 256)
        reinterpret_cast<float4*>(w_lds)[q] =
            reinterpret_cast<const float4*>(W)[q];

    constexpr int AF4 = ROWS * K / 4;
    for (int q = t; q < AF4; q += 256) {
        int r  = q / (K / 4);
        int kc = q % (K / 4);
        float4 v = make_float4(0.f, 0.f, 0.f, 0.f);
        int gr = row0 + r;
        if (gr < N)
            v = reinterpret_cast<const float4*>(A + (size_t)gr * K)[kc];
        *reinterpret_cast<float4*>(&a_lds[r * LDA + kc * 4]) = v;
    }
    __syncthreads();

    int c0 = (t % CG) * 4;
    int r0 = (t / CG) * 4;

    float4 acc[4] = {};
#pragma unroll 1
    for (int k = 0; k < K; k += 4) {
        float4 w0 = *reinterpret_cast<const float4*>(&w_lds[(k + 0) * DOUT + c0]);
        float4 w1 = *reinterpret_cast<const float4*>(&w_lds[(k + 1) * DOUT + c0]);
        float4 w2 = *reinterpret_cast<const float4*>(&w_lds[(k + 2) * DOUT + c0]);
        float4 w3 = *reinterpret_cast<const float4*>(&w_lds[(k + 3) * DOUT + c0]);
#pragma unroll
        for (int j = 0; j < 4; ++j) {
            float4 a4 = *reinterpret_cast<const float4*>(&a_lds[(r0 + j) * LDA + k]);
            acc[j].x += a4.x * w0.x + a4.y * w1.x + a4.z * w2.x + a4.w * w3.x;
            acc[j].y += a4.x * w0.y + a4.y * w1.y + a4.z * w2.y + a4.w * w3.y;
            acc[j].z += a4.x * w0.z + a4.y * w1.z + a4.z * w2.z + a4.w * w3.z;
            acc[j].w += a4.x * w0.w + a4.y * w1.w + a4.z * w2.w + a4.w * w3.w;
        }
    }

#pragma unroll
    for (int j = 0; j < 4; ++j) {
        int gr = row0 + r0 + j;
        if (gr < N) {
            float s = dis[gr];
            float4 o = acc[j];
            ushort4 pk;
            pk.x = r16(o.x * s); pk.y = r16(o.y * s);
            pk.z = r16(o.z * s); pk.w = r16(o.w * s);
            *reinterpret_cast<ushort4*>(&G16[(size_t)gr * DOUT + c0]) = pk;
        }
    }
}

// ---------------- GEMM, bias epilogue, fp32 out (final layer) ----------------
template <int K, int DOUT>
__global__ __launch_bounds__(256) void gemm_bias(const float* __restrict__ A,
                                                 const float* __restrict__ W,
                                                 const float* __restrict__ bias,
                                                 float* __restrict__ Out, int N) {
    constexpr int CG   = DOUT / 4;
    constexpr int RG   = 256 / CG;
    constexpr int ROWS = RG * 4;
    constexpr int LDA  = K + 4;

    __shared__ __align__(16) float a_lds[ROWS * LDA];
    __shared__ __align__(16) float w_lds[K * DOUT];

    int t    = threadIdx.x;
    int row0 = blockIdx.x * ROWS;

    constexpr int WF4 = K * DOUT / 4;
    for (int q = t; q < WF4; q += 256)
        reinterpret_cast<float4*>(w_lds)[q] =
            reinterpret_cast<const float4*>(W)[q];

    constexpr int AF4 = ROWS * K / 4;
    for (int q = t; q < AF4; q += 256) {
        int r  = q / (K / 4);
        int kc = q % (K / 4);
        float4 v = make_float4(0.f, 0.f, 0.f, 0.f);
        int gr = row0 + r;
        if (gr < N)
            v = reinterpret_cast<const float4*>(A + (size_t)gr * K)[kc];
        *reinterpret_cast<float4*>(&a_lds[r * LDA + kc * 4]) = v;
    }
    __syncthreads();

    int c0 = (t % CG) * 4;
    int r0 = (t / CG) * 4;

    float4 acc[4] = {};
#pragma unroll 1
    for (int k = 0; k < K; k += 4) {
        float4 w0 = *reinterpret_cast<const float4*>(&w_lds[(k + 0) * DOUT + c0]);
        float4 w1 = *reinterpret_cast<const float4*>(&w_lds[(k + 1) * DOUT + c0]);
        float4 w2 = *reinterpret_cast<const float4*>(&w_lds[(k + 2) * DOUT + c0]);
        float4 w3 = *reinterpret_cast<const float4*>(&w_lds[(k + 3) * DOUT + c0]);
#pragma unroll
        for (int j = 0; j < 4; ++j) {
            float4 a4 = *reinterpret_cast<const float4*>(&a_lds[(r0 + j) * LDA + k]);
            acc[j].x += a4.x * w0.x + a4.y * w1.x + a4.z * w2.x + a4.w * w3.x;
            acc[j].y += a4.x * w0.y + a4.y * w1.y + a4.z * w2.y + a4.w * w3.y;
            acc[j].z += a4.x * w0.z + a4.y * w1.z + a4.z * w2.z + a4.w * w3.z;
            acc[j].w += a4.x * w0.w + a4.y * w1.w + a4.z * w2.w + a4.w * w3.w;
        }
    }

    float4 b4v = *reinterpret_cast<const float4*>(&bias[c0]);
#pragma unroll
    for (int j = 0; j < 4; ++j) {
        int gr = row0 + r0 + j;
        if (gr < N) {
            float4 o = acc[j];
            o.x += b4v.x; o.y += b4v.y; o.z += b4v.z; o.w += b4v.w;
            reinterpret_cast<float4*>(Out + (size_t)gr * DOUT)[c0 / 4] = o;
        }
    }
}

// ---------------- Fused aggregate + next-layer 64->64 GEMM ------------------
// 2 nodes per wave, gathers issued jointly; dual matvec shares W LDS reads.
// Half-wave h owns node h's epilogue (a_buf row, Zout, Gout), hasB-guarded.
template <bool WRITE_F32>
__global__ __launch_bounds__(256) void agg_gemm_pair(
    const unsigned* __restrict__ G,
    const int* __restrict__ row_ptr,
    const int* __restrict__ csr_src,
    const float* __restrict__ dis,
    const float* __restrict__ bias,
    const float* __restrict__ Wn,        // [64][64] fp32
    unsigned* __restrict__ Gout,
    float* __restrict__ Zout,
    int N) {
    __shared__ __align__(16) float w_lds[64 * 64];
    __shared__ __align__(16) float a_buf[4][2][64];

    int t = threadIdx.x;
    for (int q = t; q < 64 * 64 / 4; q += 256)
        reinterpret_cast<float4*>(w_lds)[q] =
            reinterpret_cast<const float4*>(Wn)[q];
    __syncthreads();

    int wave = t >> 6, lane = t & 63;
    int h = lane >> 5, fl = lane & 31;

    int n0 = (blockIdx.x * 4 + wave) * 2;
    if (n0 >= N) return;       // wave-uniform
    int n1 = n0 + 1;
    bool hasB = (n1 < N);
    int n1c = hasB ? n1 : n0;
    int nn = h ? n1c : n0;

    int begA = row_ptr[n0];
    int endA = row_ptr[n0 + 1];
    int lenA = endA - begA;
    int begB = 0, lenB = 0;
    if (hasB) { begB = endA; lenB = row_ptr[n0 + 2] - endA; }

    float dn0 = dis[n0], dn1 = dis[n1c];
    unsigned us = G[(unsigned)nn * 32u + fl];   // own node's self-loop pair
    float2 b2 = reinterpret_cast<const float2*>(bias)[fl];

    float loA, hiA, loB, hiB;
    gather_pair_u(G, csr_src, begA, lenA, begB, lenB, lane, h, fl,
                  loA, hiA, loB, hiB);

    float dn = h ? dn1 : dn0;
    float lo = h ? loB : loA;
    float hi = h ? hiB : hiA;
    float vlo = fmaxf(dn * (lo + bf_lo(us)) + b2.x, 0.f);
    float vhi = fmaxf(dn * (hi + bf_hi(us)) + b2.y, 0.f);

    *reinterpret_cast<float2*>(&a_buf[wave][h][2 * fl]) = make_float2(vlo, vhi);
    if (WRITE_F32 && (h == 0 || hasB))
        reinterpret_cast<float2*>(Zout)[(size_t)nn * 32 + fl] =
            make_float2(vlo, vhi);

    __builtin_amdgcn_wave_barrier();   // a_buf write -> read (in-order DS)

    // dual matvec: lane owns output column `lane` for BOTH nodes; W shared
    float yA0 = 0.f, yA1 = 0.f, yA2 = 0.f, yA3 = 0.f;
    float yB0 = 0.f, yB1 = 0.f, yB2 = 0.f, yB3 = 0.f;
    for (int k = 0; k < 64; k += 4) {
        float4 a4 = *reinterpret_cast<const float4*>(&a_buf[wave][0][k]);
        float4 c4 = *reinterpret_cast<const float4*>(&a_buf[wave][1][k]);
        float w0 = w_lds[(k + 0) * 64 + lane];
        float w1 = w_lds[(k + 1) * 64 + lane];
        float w2 = w_lds[(k + 2) * 64 + lane];
        float w3 = w_lds[(k + 3) * 64 + lane];
        yA0 += a4.x * w0; yA1 += a4.y * w1; yA2 += a4.z * w2; yA3 += a4.w * w3;
        yB0 += c4.x * w0; yB1 += c4.y * w1; yB2 += c4.z * w2; yB3 += c4.w * w3;
    }
    float yA = (yA0 + yA1) + (yA2 + yA3);
    float yB = (yB0 + yB1) + (yB2 + yB3);

    float l0 = __shfl(yA, 2 * fl), h0 = __shfl(yA, 2 * fl + 1);
    float l1 = __shfl(yB, 2 * fl), h1 = __shfl(yB, 2 * fl + 1);
    float yl = h ? l1 : l0;
    float yh = h ? h1 : h0;
    if (h == 0 || hasB) {
        unsigned pk = (unsigned)r16(dn * yl) | ((unsigned)r16(dn * yh) << 16);
        Gout[(unsigned)nn * 32u + fl] = pk;
    }
}

// ---------------- Plain aggregations -----------------------------------------
// Layer 3: s3 = bf16(dis * relu(agg + b3)) table. 2 nodes/wave joint gather.
__global__ __launch_bounds__(256) void aggregate_s3(const unsigned* __restrict__ G,
                                                    const int* __restrict__ row_ptr,
                                                    const int* __restrict__ csr_src,
                                                    const float* __restrict__ dis,
                                                    const float* __restrict__ bias,
                                                    unsigned* __restrict__ Out, int N) {
    int t = threadIdx.x;
    int wave = t >> 6, lane = t & 63;
    int h = lane >> 5, fl = lane & 31;

    int n0 = (blockIdx.x * 4 + wave) * 2;
    if (n0 >= N) return;
    int n1 = n0 + 1;
    bool hasB = (n1 < N);
    int n1c = hasB ? n1 : n0;
    int nn = h ? n1c : n0;

    int begA = row_ptr[n0];
    int endA = row_ptr[n0 + 1];
    int lenA = endA - begA;
    int begB = 0, lenB = 0;
    if (hasB) { begB = endA; lenB = row_ptr[n0 + 2] - endA; }

    float dn0 = dis[n0], dn1 = dis[n1c];
    unsigned us = G[(unsigned)nn * 32u + fl];
    float2 b2 = reinterpret_cast<const float2*>(bias)[fl];

    float loA, hiA, loB, hiB;
    gather_pair_u(G, csr_src, begA, lenA, begB, lenB, lane, h, fl,
                  loA, hiA, loB, hiB);

    float dn = h ? dn1 : dn0;
    float lo = h ? loB : loA;
    float hi = h ? hiB : hiA;
    float vlo = fmaxf(dn * (lo + bf_lo(us)) + b2.x, 0.f);
    float vhi = fmaxf(dn * (hi + bf_hi(us)) + b2.y, 0.f);

    if (h == 0 || hasB) {
        // s3 = bf16(dis[n] * v) — extra dn for the reassociated layer 4
        unsigned pk = (unsigned)r16(dn * vlo) | ((unsigned)r16(dn * vhi) << 16);
        Out[(unsigned)nn * 32u + fl] = pk;
    }
}

// Layer 4 aggregate: t = dis[n]*(s3[n]+sum s3[src]) (fp32, no bias/relu).
__global__ __launch_bounds__(256) void aggregate_t(const unsigned* __restrict__ G,
                                                   const int* __restrict__ row_ptr,
                                                   const int* __restrict__ csr_src,
                                                   const float* __restrict__ dis,
                                                   float* __restrict__ Out, int N) {
    int t = threadIdx.x;
    int wave = t >> 6, lane = t & 63;
    int h = lane >> 5, fl = lane & 31;

    int n0 = (blockIdx.x * 4 + wave) * 2;
    if (n0 >= N) return;
    int n1 = n0 + 1;
    bool hasB = (n1 < N);
    int n1c = hasB ? n1 : n0;
    int nn = h ? n1c : n0;

    int begA = row_ptr[n0];
    int endA = row_ptr[n0 + 1];
    int lenA = endA - begA;
    int begB = 0, lenB = 0;
    if (hasB) { begB = endA; lenB = row_ptr[n0 + 2] - endA; }

    float dn0 = dis[n0], dn1 = dis[n1c];
    unsigned us = G[(unsigned)nn * 32u + fl];

    float loA, hiA, loB, hiB;
    gather_pair_u(G, csr_src, begA, lenA, begB, lenB, lane, h, fl,
                  loA, hiA, loB, hiB);

    float dn = h ? dn1 : dn0;
    float lo = h ? loB : loA;
    float hi = h ? hiB : hiA;

    if (h == 0 || hasB)
        reinterpret_cast<float2*>(Out)[(size_t)nn * 32 + fl] =
            make_float2(dn * (lo + bf_lo(us)), dn * (hi + bf_hi(us)));
}

// ---------------- Launch ----------------

extern "C" void kernel_launch(void* const* d_in, const int* in_sizes, int n_in,
                              void* d_out, int out_size, void* d_ws, size_t ws_size,
                              hipStream_t stream) {
    const float* x     = (const float*)d_in[0];
    const int*   edges = (const int*)d_in[1];   // [2, E] row-major
    const float* W1 = (const float*)d_in[2];
    const float* b1 = (const float*)d_in[3];
    const float* W2 = (const float*)d_in[4];
    const float* b2 = (const float*)d_in[5];
    const float* W3 = (const float*)d_in[6];
    const float* b3 = (const float*)d_in[7];
    const float* W4 = (const float*)d_in[8];
    const float* b4 = (const float*)d_in[9];

    const int DIN = 128, DH = 64;
    int N = in_sizes[0] / DIN;
    int E = in_sizes[1] / 2;

    const int* e_src = edges;
    const int* e_dst = edges + E;

    float* out   = (float*)d_out;
    float* x_hat = out;                       // [N,128]
    float* z     = out + (size_t)N * DIN;     // [N,64]

    int B    = (N + 2047) / 2048;
    int Npad = B * 2048;

    char*  ws  = (char*)d_ws;
    size_t woff = 0;
    auto carve = [&](size_t bytes) {
        void* p = ws + woff;
        woff = (woff + bytes + 255) & ~(size_t)255;
        return p;
    };
    float*    dis        = (float*)   carve((size_t)N * 4);
    int*      deg        = (int*)     carve((size_t)Npad * 4);
    int*      row_ptr    = (int*)     carve((size_t)(N + 1) * 4);
    int*      csr_src    = (int*)     carve((size_t)E * 4);
    int*      block_sums = (int*)     carve((size_t)B * 4);
    int*      block_off  = (int*)     carve((size_t)B * 4);
    unsigned* gA         = (unsigned*)carve((size_t)N * DH * 2);  // ping
    unsigned* gB         = (unsigned*)carve((size_t)N * DH * 2);  // pong
    float*    t          = (float*)   carve((size_t)N * DH * 4);  // layer-4 agg
    (void)ws_size;

    int nb_e = (E + 255) / 256;
    int nb_p = (N + 7) / 8;        // pair kernels: 4 waves x 2 nodes per block

    // CSR build
    init_k<<<(Npad + 255) / 256, 256, 0, stream>>>(deg, Npad);
    hist_deg<<<nb_e, 256, 0, stream>>>(e_dst, deg, E);
    scan_phase1<<<B, 256, 0, stream>>>(deg, block_sums);
    scan_phase2<<<1, 256, 0, stream>>>(block_sums, block_off, row_ptr, B, N);
    scan_phase3<<<B, 256, 0, stream>>>(deg, block_off, row_ptr, dis, N);
    fill_csr<<<nb_e, 256, 0, stream>>>(e_src, e_dst, row_ptr, deg, csr_src, E);

    // Layer 1 GEMM: g1 = bf16(dis*(x @ W1)) -> gA
    gemm_scale<128, 64><<<(N + 63) / 64, 256, 0, stream>>>(
        x, W1, dis, (ushort*)gA, N);

    // Fused 1->2: h = relu(agg(gA)+b1); gB = bf16(dis*(h@W2))
    agg_gemm_pair<false><<<nb_p, 256, 0, stream>>>(
        gA, row_ptr, csr_src, dis, b1, W2, gB, nullptr, N);

    // Fused 2->3: z = relu(agg(gB)+b2) -> d_out; gA = bf16(dis*(z@W3))
    agg_gemm_pair<true><<<nb_p, 256, 0, stream>>>(
        gB, row_ptr, csr_src, dis, b2, W3, gA, z, N);

    // Layer 3: s3 = bf16(dis * relu(agg(gA)+b3)) -> gB
    aggregate_s3<<<nb_p, 256, 0, stream>>>(
        gA, row_ptr, csr_src, dis, b3, gB, N);

    // Layer 4 (unfused): t = dis*agg(gB); x_hat = t @ W4 + b4
    aggregate_t<<<nb_p, 256, 0, stream>>>(
        gB, row_ptr, csr_src, dis, t, N);
    gemm_bias<64, 128><<<(N + 31) / 32, 256, 0, stream>>>(t, W4, b4, x_hat, N);
}

// Round 5
// 286.119 us; speedup vs baseline: 1.1347x; 1.0441x over previous
//
#include <hip/hip_runtime.h>
#include <hip/hip_bf16.h>

// DOMINANT GCN autoencoder on MI355X.
// R15: halve gather vmem instruction count (theory: passes are vmem
// issue-bound, not latency-exposure-bound — R14's MLP doubling only gave -6%).
//  - 16-lane node groups x uint2 loads: one 64-lane load serves 4 edges
//    (4 groups x 128B contiguous). Gather insts/pass 345k -> 172k.
//  - lane holds features 4f..4f+3; parity groups combined via shfl_xor(16).
//  - wave-uniform batches (pM = max over both nodes), cndmask predication,
//    all __shfl fully active (R13 discipline). deg>32 spill memory-indexed.
//  - matvec + Gout epilogue in fused kernels unchanged from R14 (verified).
// CSR build, layer-1 GEMM, layer-4 GEMM unchanged.

// ---------------- CSR build ----------------

__global__ __launch_bounds__(256) void init_k(int* __restrict__ deg, int Npad) {
    int i = blockIdx.x * 256 + threadIdx.x;
    if (i < Npad) deg[i] = 0;
}

__global__ __launch_bounds__(256) void hist_deg(const int* __restrict__ dst,
                                                int* __restrict__ deg, int E) {
    int e = blockIdx.x * 256 + threadIdx.x;
    if (e < E) atomicAdd(&deg[dst[e]], 1);
}

__global__ __launch_bounds__(256) void scan_phase1(const int* __restrict__ deg,
                                                   int* __restrict__ block_sums) {
    int b = blockIdx.x, t = threadIdx.x;
    const int4* p = reinterpret_cast<const int4*>(deg + (size_t)b * 2048);
    int4 a = p[t * 2], c = p[t * 2 + 1];
    int s = a.x + a.y + a.z + a.w + c.x + c.y + c.z + c.w;
#pragma unroll
    for (int off = 32; off; off >>= 1) s += __shfl_down(s, off);
    __shared__ int wsum[4];
    if ((t & 63) == 0) wsum[t >> 6] = s;
    __syncthreads();
    if (t == 0) block_sums[b] = wsum[0] + wsum[1] + wsum[2] + wsum[3];
}

__global__ __launch_bounds__(256) void scan_phase2(const int* __restrict__ block_sums,
                                                   int* __restrict__ block_off,
                                                   int* __restrict__ row_ptr,
                                                   int B, int N) {
    __shared__ int s[256];
    int t = threadIdx.x;
    int v = (t < B) ? block_sums[t] : 0;
    s[t] = v;
    __syncthreads();
#pragma unroll
    for (int off = 1; off < 256; off <<= 1) {
        int u = (t >= off) ? s[t - off] : 0;
        __syncthreads();
        s[t] += u;
        __syncthreads();
    }
    if (t < B) block_off[t] = s[t] - v;
    if (t == 255) row_ptr[N] = s[255];
}

__global__ __launch_bounds__(256) void scan_phase3(const int* __restrict__ deg,
                                                   const int* __restrict__ block_off,
                                                   int* __restrict__ row_ptr,
                                                   float* __restrict__ dis, int N) {
    int b = blockIdx.x, t = threadIdx.x;
    int base = b * 2048 + t * 8;
    const int4* p = reinterpret_cast<const int4*>(deg + base);
    int4 a = p[0], c = p[1];
    int d[8] = {a.x, a.y, a.z, a.w, c.x, c.y, c.z, c.w};
    int pre[8], s = 0;
#pragma unroll
    for (int j = 0; j < 8; ++j) { pre[j] = s; s += d[j]; }
    __shared__ int ls[256];
    ls[t] = s;
    __syncthreads();
#pragma unroll
    for (int off = 1; off < 256; off <<= 1) {
        int u = (t >= off) ? ls[t - off] : 0;
        __syncthreads();
        ls[t] += u;
        __syncthreads();
    }
    int excl = ls[t] - s + block_off[b];
#pragma unroll
    for (int j = 0; j < 8; ++j) {
        int i = base + j;
        if (i < N) {
            row_ptr[i] = excl + pre[j];
            dis[i] = rsqrtf((float)(d[j] + 1));
        }
    }
}

__global__ __launch_bounds__(256) void fill_csr(const int* __restrict__ src,
                                                const int* __restrict__ dst,
                                                const int* __restrict__ row_ptr,
                                                int* __restrict__ deg,
                                                int* __restrict__ csr_src, int E) {
    int e = blockIdx.x * 256 + threadIdx.x;
    if (e < E) {
        int d = dst[e];
        int old = atomicSub(&deg[d], 1);
        csr_src[row_ptr[d] + old - 1] = src[e];
    }
}

// ---------------- helpers ----------------

__device__ __forceinline__ ushort r16(float f) {
    __hip_bfloat16 h = __float2bfloat16(f);   // round-to-nearest-even
    return *reinterpret_cast<ushort*>(&h);
}
__device__ __forceinline__ float bf_lo(unsigned u) {
    return __builtin_bit_cast(float, u << 16);
}
__device__ __forceinline__ float bf_hi(unsigned u) {
    return __builtin_bit_cast(float, u & 0xFFFF0000u);
}

// Dual-node gather-sum, uint2 edition. 4 groups of 16 lanes:
//   grp 0: node A, even edges | grp 1: node A, odd edges
//   grp 2: node B, even edges | grp 3: node B, odd edges
// Lane f (=lane&15) covers features 4f..4f+3 (uint2 at row offset 2f).
// Indices preloaded on lanes 0..31 (replicated upper half); __shfl sources
// are always <=31. Batch bound pM is wave-uniform (max over A,B); slot
// validity via cndmask zeroing (addresses always valid). deg>32 spill is
// memory-indexed (no shfl -> divergence-safe). Returns own-half node's
// (h = lane>>5: 0->A, 1->B) neighbor sums s0..s3 on all lanes of that half.
__device__ __forceinline__ void gather_pair_u2(const unsigned* __restrict__ G,
                                               const int* __restrict__ csr_src,
                                               int begA, int lenA,
                                               int begB, int lenB, int lane,
                                               float& s0o, float& s1o,
                                               float& s2o, float& s3o) {
    int l32 = lane & 31;
    int idxA = 0, idxB = 0;
    if (lenA > 0) idxA = csr_src[begA + (l32 < lenA ? l32 : lenA - 1)];
    if (lenB > 0) idxB = csr_src[begB + (l32 < lenB ? l32 : lenB - 1)];

    int grp     = lane >> 4;
    int p       = grp & 1;       // edge parity
    int nodeSel = grp >> 1;      // 0=A, 1=B (== lane>>5)
    int f       = lane & 15;

    int cA = lenA < 32 ? lenA : 32;
    int cB = lenB < 32 ? lenB : 32;
    int cOwn = nodeSel ? cB : cA;
    int cM = cA > cB ? cA : cB;
    int pM = (cM + 1) >> 1;      // wave-uniform batch bound

    float a0 = 0.f, a1 = 0.f, a2 = 0.f, a3 = 0.f;
    float b0 = 0.f, b1 = 0.f, b2 = 0.f, b3 = 0.f;

    for (int k = 0; k < pM; k += 8) {
        uint2 u[8];
        int ee[8];
#pragma unroll
        for (int i = 0; i < 8; ++i) {
            int e = p + 2 * (k + i);           // <= 31 always
            ee[i] = e;
            int sA = __shfl(idxA, e);
            int sB = __shfl(idxB, e);
            int s = nodeSel ? sB : sA;
            u[i] = *reinterpret_cast<const uint2*>(G + (unsigned)s * 32u + 2 * f);
        }
#pragma unroll
        for (int i = 0; i < 8; ++i) {
            unsigned ux = (ee[i] < cOwn) ? u[i].x : 0u;   // cndmask
            unsigned uy = (ee[i] < cOwn) ? u[i].y : 0u;
            if (i & 1) {
                b0 += bf_lo(ux); b1 += bf_hi(ux);
                b2 += bf_lo(uy); b3 += bf_hi(uy);
            } else {
                a0 += bf_lo(ux); a1 += bf_hi(ux);
                a2 += bf_lo(uy); a3 += bf_hi(uy);
            }
        }
    }
    // deg > 32 spill: own node's parity-p edges, memory-indexed (no shfl)
    int begOwn = nodeSel ? begB : begA;
    int lenOwn = nodeSel ? lenB : lenA;
    for (int e2 = 32 + p; e2 < lenOwn; e2 += 2) {
        int s = csr_src[begOwn + e2];
        uint2 v = *reinterpret_cast<const uint2*>(G + (unsigned)s * 32u + 2 * f);
        a0 += bf_lo(v.x); a1 += bf_hi(v.x);
        a2 += bf_lo(v.y); a3 += bf_hi(v.y);
    }

    float r0 = a0 + b0, r1 = a1 + b1, r2 = a2 + b2, r3 = a3 + b3;
    r0 += __shfl_xor(r0, 16);   // combine parity groups (all lanes active)
    r1 += __shfl_xor(r1, 16);
    r2 += __shfl_xor(r2, 16);
    r3 += __shfl_xor(r3, 16);
    s0o = r0; s1o = r1; s2o = r2; s3o = r3;
}

// ---------------- GEMM, row-scale + bf16 epilogue (layer 1) ----------------
template <int K, int DOUT>
__global__ __launch_bounds__(256) void gemm_scale(const float* __restrict__ A,
                                                  const float* __restrict__ W,
                                                  const float* __restrict__ dis,
                                                  ushort* __restrict__ G16, int N) {
    constexpr int CG   = DOUT / 4;
    constexpr int RG   = 256 / CG;
    constexpr int ROWS = RG * 4;
    constexpr int LDA  = K + 4;

    __shared__ __align__(16) float a_lds[ROWS * LDA];
    __shared__ __align__(16) float w_lds[K * DOUT];

    int t    = threadIdx.x;
    int row0 = blockIdx.x * ROWS;

    constexpr int WF4 = K * DOUT / 4;
    for (int q = t; q < WF4; q += 256)
        reinterpret_cast<float4*>(w_lds)[q] =
            reinterpret_cast<const float4*>(W)[q];

    constexpr int AF4 = ROWS * K / 4;
    for (int q = t; q < AF4; q += 256) {
        int r  = q / (K / 4);
        int kc = q % (K / 4);
        float4 v = make_float4(0.f, 0.f, 0.f, 0.f);
        int gr = row0 + r;
        if (gr < N)
            v = reinterpret_cast<const float4*>(A + (size_t)gr * K)[kc];
        *reinterpret_cast<float4*>(&a_lds[r * LDA + kc * 4]) = v;
    }
    __syncthreads();

    int c0 = (t % CG) * 4;
    int r0 = (t / CG) * 4;

    float4 acc[4] = {};
#pragma unroll 1
    for (int k = 0; k < K; k += 4) {
        float4 w0 = *reinterpret_cast<const float4*>(&w_lds[(k + 0) * DOUT + c0]);
        float4 w1 = *reinterpret_cast<const float4*>(&w_lds[(k + 1) * DOUT + c0]);
        float4 w2 = *reinterpret_cast<const float4*>(&w_lds[(k + 2) * DOUT + c0]);
        float4 w3 = *reinterpret_cast<const float4*>(&w_lds[(k + 3) * DOUT + c0]);
#pragma unroll
        for (int j = 0; j < 4; ++j) {
            float4 a4 = *reinterpret_cast<const float4*>(&a_lds[(r0 + j) * LDA + k]);
            acc[j].x += a4.x * w0.x + a4.y * w1.x + a4.z * w2.x + a4.w * w3.x;
            acc[j].y += a4.x * w0.y + a4.y * w1.y + a4.z * w2.y + a4.w * w3.y;
            acc[j].z += a4.x * w0.z + a4.y * w1.z + a4.z * w2.z + a4.w * w3.z;
            acc[j].w += a4.x * w0.w + a4.y * w1.w + a4.z * w2.w + a4.w * w3.w;
        }
    }

#pragma unroll
    for (int j = 0; j < 4; ++j) {
        int gr = row0 + r0 + j;
        if (gr < N) {
            float s = dis[gr];
            float4 o = acc[j];
            ushort4 pk;
            pk.x = r16(o.x * s); pk.y = r16(o.y * s);
            pk.z = r16(o.z * s); pk.w = r16(o.w * s);
            *reinterpret_cast<ushort4*>(&G16[(size_t)gr * DOUT + c0]) = pk;
        }
    }
}

// ---------------- GEMM, bias epilogue, fp32 out (final layer) ----------------
template <int K, int DOUT>
__global__ __launch_bounds__(256) void gemm_bias(const float* __restrict__ A,
                                                 const float* __restrict__ W,
                                                 const float* __restrict__ bias,
                                                 float* __restrict__ Out, int N) {
    constexpr int CG   = DOUT / 4;
    constexpr int RG   = 256 / CG;
    constexpr int ROWS = RG * 4;
    constexpr int LDA  = K + 4;

    __shared__ __align__(16) float a_lds[ROWS * LDA];
    __shared__ __align__(16) float w_lds[K * DOUT];

    int t    = threadIdx.x;
    int row0 = blockIdx.x * ROWS;

    constexpr int WF4 = K * DOUT / 4;
    for (int q = t; q < WF4; q += 256)
        reinterpret_cast<float4*>(w_lds)[q] =
            reinterpret_cast<const float4*>(W)[q];

    constexpr int AF4 = ROWS * K / 4;
    for (int q = t; q < AF4; q += 256) {
        int r  = q / (K / 4);
        int kc = q % (K / 4);
        float4 v = make_float4(0.f, 0.f, 0.f, 0.f);
        int gr = row0 + r;
        if (gr < N)
            v = reinterpret_cast<const float4*>(A + (size_t)gr * K)[kc];
        *reinterpret_cast<float4*>(&a_lds[r * LDA + kc * 4]) = v;
    }
    __syncthreads();

    int c0 = (t % CG) * 4;
    int r0 = (t / CG) * 4;

    float4 acc[4] = {};
#pragma unroll 1
    for (int k = 0; k < K; k += 4) {
        float4 w0 = *reinterpret_cast<const float4*>(&w_lds[(k + 0) * DOUT + c0]);
        float4 w1 = *reinterpret_cast<const float4*>(&w_lds[(k + 1) * DOUT + c0]);
        float4 w2 = *reinterpret_cast<const float4*>(&w_lds[(k + 2) * DOUT + c0]);
        float4 w3 = *reinterpret_cast<const float4*>(&w_lds[(k + 3) * DOUT + c0]);
#pragma unroll
        for (int j = 0; j < 4; ++j) {
            float4 a4 = *reinterpret_cast<const float4*>(&a_lds[(r0 + j) * LDA + k]);
            acc[j].x += a4.x * w0.x + a4.y * w1.x + a4.z * w2.x + a4.w * w3.x;
            acc[j].y += a4.x * w0.y + a4.y * w1.y + a4.z * w2.y + a4.w * w3.y;
            acc[j].z += a4.x * w0.z + a4.y * w1.z + a4.z * w2.z + a4.w * w3.z;
            acc[j].w += a4.x * w0.w + a4.y * w1.w + a4.z * w2.w + a4.w * w3.w;
        }
    }

    float4 b4v = *reinterpret_cast<const float4*>(&bias[c0]);
#pragma unroll
    for (int j = 0; j < 4; ++j) {
        int gr = row0 + r0 + j;
        if (gr < N) {
            float4 o = acc[j];
            o.x += b4v.x; o.y += b4v.y; o.z += b4v.z; o.w += b4v.w;
            reinterpret_cast<float4*>(Out + (size_t)gr * DOUT)[c0 / 4] = o;
        }
    }
}

// ---------------- Fused aggregate + next-layer 64->64 GEMM ------------------
// 2 nodes per wave; uint2 group gather; dual matvec shares W LDS reads.
// a_buf fill + Zout from groups 0/2 (float4); matvec + Gout epilogue = R14.
template <bool WRITE_F32>
__global__ __launch_bounds__(256) void agg_gemm_pair(
    const unsigned* __restrict__ G,
    const int* __restrict__ row_ptr,
    const int* __restrict__ csr_src,
    const float* __restrict__ dis,
    const float* __restrict__ bias,
    const float* __restrict__ Wn,        // [64][64] fp32
    unsigned* __restrict__ Gout,
    float* __restrict__ Zout,
    int N) {
    __shared__ __align__(16) float w_lds[64 * 64];
    __shared__ __align__(16) float a_buf[4][2][64];

    int t = threadIdx.x;
    for (int q = t; q < 64 * 64 / 4; q += 256)
        reinterpret_cast<float4*>(w_lds)[q] =
            reinterpret_cast<const float4*>(Wn)[q];
    __syncthreads();

    int wave = t >> 6, lane = t & 63;
    int h = lane >> 5, fl = lane & 31;
    int grp = lane >> 4, f = lane & 15;

    int n0 = (blockIdx.x * 4 + wave) * 2;
    if (n0 >= N) return;       // wave-uniform
    int n1 = n0 + 1;
    bool hasB = (n1 < N);
    int n1c = hasB ? n1 : n0;
    int nn = h ? n1c : n0;

    int begA = row_ptr[n0];
    int endA = row_ptr[n0 + 1];
    int lenA = endA - begA;
    int begB = 0, lenB = 0;
    if (hasB) { begB = endA; lenB = row_ptr[n0 + 2] - endA; }

    float dn0 = dis[n0], dn1 = dis[n1c];
    uint2 us2 = *reinterpret_cast<const uint2*>(G + (size_t)nn * 32 + 2 * f);
    float4 b4 = reinterpret_cast<const float4*>(bias)[f];

    float s0, s1, s2, s3;
    gather_pair_u2(G, csr_src, begA, lenA, begB, lenB, lane, s0, s1, s2, s3);

    float dn = h ? dn1 : dn0;
    float v0 = fmaxf(dn * (s0 + bf_lo(us2.x)) + b4.x, 0.f);
    float v1 = fmaxf(dn * (s1 + bf_hi(us2.x)) + b4.y, 0.f);
    float v2 = fmaxf(dn * (s2 + bf_lo(us2.y)) + b4.z, 0.f);
    float v3 = fmaxf(dn * (s3 + bf_hi(us2.y)) + b4.w, 0.f);

    if ((grp & 1) == 0)    // groups 0,2 own their half-node's row
        *reinterpret_cast<float4*>(&a_buf[wave][h][4 * f]) =
            make_float4(v0, v1, v2, v3);
    if (WRITE_F32 && (grp == 0 || (grp == 2 && hasB)))
        *reinterpret_cast<float4*>(Zout + (size_t)nn * 64 + 4 * f) =
            make_float4(v0, v1, v2, v3);

    __builtin_amdgcn_wave_barrier();   // a_buf write -> read (in-order DS)

    // dual matvec: lane owns output column `lane` for BOTH nodes; W shared
    float yA0 = 0.f, yA1 = 0.f, yA2 = 0.f, yA3 = 0.f;
    float yB0 = 0.f, yB1 = 0.f, yB2 = 0.f, yB3 = 0.f;
    for (int k = 0; k < 64; k += 4) {
        float4 a4 = *reinterpret_cast<const float4*>(&a_buf[wave][0][k]);
        float4 c4 = *reinterpret_cast<const float4*>(&a_buf[wave][1][k]);
        float w0 = w_lds[(k + 0) * 64 + lane];
        float w1 = w_lds[(k + 1) * 64 + lane];
        float w2 = w_lds[(k + 2) * 64 + lane];
        float w3 = w_lds[(k + 3) * 64 + lane];
        yA0 += a4.x * w0; yA1 += a4.y * w1; yA2 += a4.z * w2; yA3 += a4.w * w3;
        yB0 += c4.x * w0; yB1 += c4.y * w1; yB2 += c4.z * w2; yB3 += c4.w * w3;
    }
    float yA = (yA0 + yA1) + (yA2 + yA3);
    float yB = (yB0 + yB1) + (yB2 + yB3);

    float l0 = __shfl(yA, 2 * fl), h0 = __shfl(yA, 2 * fl + 1);
    float l1 = __shfl(yB, 2 * fl), h1 = __shfl(yB, 2 * fl + 1);
    float yl = h ? l1 : l0;
    float yh = h ? h1 : h0;
    if (h == 0 || hasB) {
        unsigned pk = (unsigned)r16(dn * yl) | ((unsigned)r16(dn * yh) << 16);
        Gout[(unsigned)nn * 32u + fl] = pk;
    }
}

// ---------------- Plain aggregations -----------------------------------------
// Layer 3: s3 = bf16(dis * relu(agg + b3)) table. 2 nodes/wave, uint2 gather.
__global__ __launch_bounds__(256) void aggregate_s3(const unsigned* __restrict__ G,
                                                    const int* __restrict__ row_ptr,
                                                    const int* __restrict__ csr_src,
                                                    const float* __restrict__ dis,
                                                    const float* __restrict__ bias,
                                                    unsigned* __restrict__ Out, int N) {
    int t = threadIdx.x;
    int wave = t >> 6, lane = t & 63;
    int h = lane >> 5;
    int grp = lane >> 4, f = lane & 15;

    int n0 = (blockIdx.x * 4 + wave) * 2;
    if (n0 >= N) return;
    int n1 = n0 + 1;
    bool hasB = (n1 < N);
    int n1c = hasB ? n1 : n0;
    int nn = h ? n1c : n0;

    int begA = row_ptr[n0];
    int endA = row_ptr[n0 + 1];
    int lenA = endA - begA;
    int begB = 0, lenB = 0;
    if (hasB) { begB = endA; lenB = row_ptr[n0 + 2] - endA; }

    float dn0 = dis[n0], dn1 = dis[n1c];
    uint2 us2 = *reinterpret_cast<const uint2*>(G + (size_t)nn * 32 + 2 * f);
    float4 b4 = reinterpret_cast<const float4*>(bias)[f];

    float s0, s1, s2, s3;
    gather_pair_u2(G, csr_src, begA, lenA, begB, lenB, lane, s0, s1, s2, s3);

    float dn = h ? dn1 : dn0;
    float o0 = fmaxf(dn * (s0 + bf_lo(us2.x)) + b4.x, 0.f);
    float o1 = fmaxf(dn * (s1 + bf_hi(us2.x)) + b4.y, 0.f);
    float o2 = fmaxf(dn * (s2 + bf_lo(us2.y)) + b4.z, 0.f);
    float o3 = fmaxf(dn * (s3 + bf_hi(us2.y)) + b4.w, 0.f);

    if (grp == 0 || (grp == 2 && hasB)) {
        // s3 = bf16(dis[n] * v) — extra dn for the reassociated layer 4
        uint2 pk2;
        pk2.x = (unsigned)r16(dn * o0) | ((unsigned)r16(dn * o1) << 16);
        pk2.y = (unsigned)r16(dn * o2) | ((unsigned)r16(dn * o3) << 16);
        *reinterpret_cast<uint2*>(Out + (size_t)nn * 32 + 2 * f) = pk2;
    }
}

// Layer 4 aggregate: t = dis[n]*(s3[n]+sum s3[src]) (fp32, no bias/relu).
__global__ __launch_bounds__(256) void aggregate_t(const unsigned* __restrict__ G,
                                                   const int* __restrict__ row_ptr,
                                                   const int* __restrict__ csr_src,
                                                   const float* __restrict__ dis,
                                                   float* __restrict__ Out, int N) {
    int t = threadIdx.x;
    int wave = t >> 6, lane = t & 63;
    int h = lane >> 5;
    int grp = lane >> 4, f = lane & 15;

    int n0 = (blockIdx.x * 4 + wave) * 2;
    if (n0 >= N) return;
    int n1 = n0 + 1;
    bool hasB = (n1 < N);
    int n1c = hasB ? n1 : n0;
    int nn = h ? n1c : n0;

    int begA = row_ptr[n0];
    int endA = row_ptr[n0 + 1];
    int lenA = endA - begA;
    int begB = 0, lenB = 0;
    if (hasB) { begB = endA; lenB = row_ptr[n0 + 2] - endA; }

    float dn0 = dis[n0], dn1 = dis[n1c];
    uint2 us2 = *reinterpret_cast<const uint2*>(G + (size_t)nn * 32 + 2 * f);

    float s0, s1, s2, s3;
    gather_pair_u2(G, csr_src, begA, lenA, begB, lenB, lane, s0, s1, s2, s3);

    float dn = h ? dn1 : dn0;
    if (grp == 0 || (grp == 2 && hasB))
        *reinterpret_cast<float4*>(Out + (size_t)nn * 64 + 4 * f) =
            make_float4(dn * (s0 + bf_lo(us2.x)), dn * (s1 + bf_hi(us2.x)),
                        dn * (s2 + bf_lo(us2.y)), dn * (s3 + bf_hi(us2.y)));
}

// ---------------- Launch ----------------

extern "C" void kernel_launch(void* const* d_in, const int* in_sizes, int n_in,
                              void* d_out, int out_size, void* d_ws, size_t ws_size,
                              hipStream_t stream) {
    const float* x     = (const float*)d_in[0];
    const int*   edges = (const int*)d_in[1];   // [2, E] row-major
    const float* W1 = (const float*)d_in[2];
    const float* b1 = (const float*)d_in[3];
    const float* W2 = (const float*)d_in[4];
    const float* b2 = (const float*)d_in[5];
    const float* W3 = (const float*)d_in[6];
    const float* b3 = (const float*)d_in[7];
    const float* W4 = (const float*)d_in[8];
    const float* b4 = (const float*)d_in[9];

    const int DIN = 128, DH = 64;
    int N = in_sizes[0] / DIN;
    int E = in_sizes[1] / 2;

    const int* e_src = edges;
    const int* e_dst = edges + E;

    float* out   = (float*)d_out;
    float* x_hat = out;                       // [N,128]
    float* z     = out + (size_t)N * DIN;     // [N,64]

    int B    = (N + 2047) / 2048;
    int Npad = B * 2048;

    char*  ws  = (char*)d_ws;
    size_t woff = 0;
    auto carve = [&](size_t bytes) {
        void* p = ws + woff;
        woff = (woff + bytes + 255) & ~(size_t)255;
        return p;
    };
    float*    dis        = (float*)   carve((size_t)N * 4);
    int*      deg        = (int*)     carve((size_t)Npad * 4);
    int*      row_ptr    = (int*)     carve((size_t)(N + 1) * 4);
    int*      csr_src    = (int*)     carve((size_t)E * 4);
    int*      block_sums = (int*)     carve((size_t)B * 4);
    int*      block_off  = (int*)     carve((size_t)B * 4);
    unsigned* gA         = (unsigned*)carve((size_t)N * DH * 2);  // ping
    unsigned* gB         = (unsigned*)carve((size_t)N * DH * 2);  // pong
    float*    t          = (float*)   carve((size_t)N * DH * 4);  // layer-4 agg
    (void)ws_size;

    int nb_e = (E + 255) / 256;
    int nb_p = (N + 7) / 8;        // pair kernels: 4 waves x 2 nodes per block

    // CSR build
    init_k<<<(Npad + 255) / 256, 256, 0, stream>>>(deg, Npad);
    hist_deg<<<nb_e, 256, 0, stream>>>(e_dst, deg, E);
    scan_phase1<<<B, 256, 0, stream>>>(deg, block_sums);
    scan_phase2<<<1, 256, 0, stream>>>(block_sums, block_off, row_ptr, B, N);
    scan_phase3<<<B, 256, 0, stream>>>(deg, block_off, row_ptr, dis, N);
    fill_csr<<<nb_e, 256, 0, stream>>>(e_src, e_dst, row_ptr, deg, csr_src, E);

    // Layer 1 GEMM: g1 = bf16(dis*(x @ W1)) -> gA
    gemm_scale<128, 64><<<(N + 63) / 64, 256, 0, stream>>>(
        x, W1, dis, (ushort*)gA, N);

    // Fused 1->2: h = relu(agg(gA)+b1); gB = bf16(dis*(h@W2))
    agg_gemm_pair<false><<<nb_p, 256, 0, stream>>>(
        gA, row_ptr, csr_src, dis, b1, W2, gB, nullptr, N);

    // Fused 2->3: z = relu(agg(gB)+b2) -> d_out; gA = bf16(dis*(z@W3))
    agg_gemm_pair<true><<<nb_p, 256, 0, stream>>>(
        gB, row_ptr, csr_src, dis, b2, W3, gA, z, N);

    // Layer 3: s3 = bf16(dis * relu(agg(gA)+b3)) -> gB
    aggregate_s3<<<nb_p, 256, 0, stream>>>(
        gA, row_ptr, csr_src, dis, b3, gB, N);

    // Layer 4 (unfused): t = dis*agg(gB); x_hat = t @ W4 + b4
    aggregate_t<<<nb_p, 256, 0, stream>>>(
        gB, row_ptr, csr_src, dis, t, N);
    gemm_bias<64, 128><<<(N + 31) / 32, 256, 0, stream>>>(t, W4, b4, x_hat, N);
}